// Round 6
// baseline (583.044 us; speedup 1.0000x reference)
//
#include <hip/hip_runtime.h>
#include <cstdint>
#include <cstddef>

// Problem constants (from reference setup_inputs)
#define C_ 4
#define B_ 128
#define G_ 2048
#define S_ 32
#define L_ 3
#define NSTEP_ 3
#define GAMMA_ 0.01f
#define INVG_ 100.0f
#define CG_ (C_ * G_)                  // 8192 (c,g) pairs
#define NELEM_ ((size_t)C_ * G_ * B_)  // 1048576
#define PERC_ ((size_t)G_ * B_)        // 262144 (power of 2)

// Lazy-normalization slots: slots[k] = float-bits of global maxes (all > 0 so
// uint bit-compare == float compare). slot 0 stays 0 (scale 1 for step 0);
// step k writes m1 -> 2k+1, m2 -> 2k+2. Stream order = cross-kernel barrier.

__device__ __forceinline__ float slot_scale(const uint32_t* slots, int i) {
  const float m = __uint_as_float(
      __hip_atomic_load(slots + i, __ATOMIC_RELAXED, __HIP_MEMORY_SCOPE_AGENT));
  return (m > 1.0f) ? (1.0f / m) : 1.0f;
}

// ---------------------------------------------------------------------------
// k_init: Xt[g,b] = x[b,g] (tiled transpose, both sides coalesced)
// ---------------------------------------------------------------------------
__global__ __launch_bounds__(256) void k_init(const float* __restrict__ x,
                                              float* __restrict__ Xt) {
  __shared__ float tile[32][33];
  const int g0 = blockIdx.x * 32, b0 = blockIdx.y * 32;
  const int tx = threadIdx.x;
  for (int i = threadIdx.y; i < 32; i += 8)
    tile[i][tx] = x[(size_t)(b0 + i) * G_ + g0 + tx];  // tile[b][g]
  __syncthreads();
  for (int j = threadIdx.y; j < 32; j += 8)
    Xt[(size_t)(g0 + j) * B_ + b0 + tx] = tile[tx][j];
}

// ---------------------------------------------------------------------------
// k_gather: one block (128 thr) per cg; tid IS the b index. Indices staged
// to LDS (broadcast reads, conflict-free). TWO-PASS LSE with a max reduction
// between load pass and exp pass: the max over body[0..31] keeps every
// body[s] live across the full first pass, which FORCES the compiler to
// allocate ~64 VGPRs and issue the 96 row-loads in bulk (R1: VGPR 64,
// VALUBusy 42%). R4/R5 dropped the max pass and LLVM register-minimized to
// VGPR 20-24, serializing ~32 L2 round-trips per wave (VALUBusy 10-13%,
// 3.4x slower). The max pass IS the MLP-forcing structure — do not remove.
// Previous-step scale folded: body stays raw; exp arg = fma(body, s3I, -m*s3I).
// ---------------------------------------------------------------------------
__global__ __launch_bounds__(128) void k_gather(
    const float* __restrict__ src, size_t cstride, const int* __restrict__ Idx,
    float* __restrict__ Lb, uint32_t* __restrict__ slots, int prev_slot,
    int out_slot) {
  __shared__ int sidx[S_ * L_];
  __shared__ uint32_t smax;
  const int tid = threadIdx.x;
  const int cg = blockIdx.x;
  const int c = cg >> 11;  // cg / G_
  if (tid == 0) smax = 0u;
  if (tid < S_ * L_) sidx[tid] = Idx[(size_t)cg * (S_ * L_) + tid];
  const float sc = slot_scale(slots, prev_slot);
  const float s3 = sc * sc * sc;   // pending normalization^3 (lazy)
  const float s3I = s3 * INVG_;
  __syncthreads();

  const float* base = src + (size_t)c * cstride + tid;
  float body[S_];
#pragma unroll
  for (int s = 0; s < S_; ++s) {
    const float v0 = base[(size_t)sidx[3 * s + 0] * B_];
    const float v1 = base[(size_t)sidx[3 * s + 1] * B_];
    const float v2 = base[(size_t)sidx[3 * s + 2] * B_];
    body[s] = (v0 * v1) * v2;
  }
  // max reduction (pairwise tree, also the liveness anchor for body[])
  float m0 = body[0], m1 = body[1], m2 = body[2], m3 = body[3];
#pragma unroll
  for (int s = 4; s < S_; s += 4) {
    m0 = fmaxf(m0, body[s]);
    m1 = fmaxf(m1, body[s + 1]);
    m2 = fmaxf(m2, body[s + 2]);
    m3 = fmaxf(m3, body[s + 3]);
  }
  const float m = fmaxf(fmaxf(m0, m1), fmaxf(m2, m3));
  const float mneg = -m * s3I;  // exp arg offset
  float acc0 = 0.0f, acc1 = 0.0f;
#pragma unroll
  for (int s = 0; s < S_; ++s) {
    const float e = __expf(fmaf(body[s], s3I, mneg));
    if (s & 1) acc1 += e; else acc0 += e;  // split dependency chain
  }
  const float lse = m * s3 + GAMMA_ * __logf(acc0 + acc1);
  Lb[(size_t)cg * B_ + tid] = lse;

  atomicMax(&smax, __float_as_uint(lse));
  __syncthreads();
  if (tid == 0) atomicMax(slots + out_slot, smax);
}

// ---------------------------------------------------------------------------
// k_elem: A = softor2(R_prev * sprev, lse1 * s1), float4-vectorized,
// with global-max side computation.
// ---------------------------------------------------------------------------
__global__ __launch_bounds__(256) void k_elem(float* __restrict__ A,
                                              const float* __restrict__ Xt,
                                              const float* __restrict__ Lb,
                                              uint32_t* __restrict__ slots,
                                              int step, int prev_slot,
                                              int m1_slot, int out_slot) {
  __shared__ uint32_t smax;
  if (threadIdx.x == 0) smax = 0u;
  __syncthreads();
  const float spI = slot_scale(slots, prev_slot) * INVG_;
  const float s1I = slot_scale(slots, m1_slot) * INVG_;
  float tmax = 0.0f;
  const size_t n4 = NELEM_ / 4;
  const size_t stride = (size_t)gridDim.x * blockDim.x;
  float4* A4 = (float4*)A;
  const float4* X4 = (const float4*)Xt;
  const float4* L4 = (const float4*)Lb;
  for (size_t i = (size_t)blockIdx.x * blockDim.x + threadIdx.x; i < n4;
       i += stride) {
    const float4 R = (step == 0) ? X4[i & (PERC_ / 4 - 1)] : A4[i];
    const float4 ce = L4[i];
    float4 o;
    o.x = 0.5f + GAMMA_ * __logf(__expf(fmaf(R.x, spI, -50.0f)) +
                                 __expf(fmaf(ce.x, s1I, -50.0f)));
    o.y = 0.5f + GAMMA_ * __logf(__expf(fmaf(R.y, spI, -50.0f)) +
                                 __expf(fmaf(ce.y, s1I, -50.0f)));
    o.z = 0.5f + GAMMA_ * __logf(__expf(fmaf(R.z, spI, -50.0f)) +
                                 __expf(fmaf(ce.z, s1I, -50.0f)));
    o.w = 0.5f + GAMMA_ * __logf(__expf(fmaf(R.w, spI, -50.0f)) +
                                 __expf(fmaf(ce.w, s1I, -50.0f)));
    A4[i] = o;
    tmax = fmaxf(fmaxf(fmaxf(o.x, o.y), fmaxf(o.z, o.w)), tmax);
  }
  atomicMax(&smax, __float_as_uint(tmax));
  __syncthreads();
  if (threadIdx.x == 0) atomicMax(slots + out_slot, smax);
}

// ---------------------------------------------------------------------------
// k_out: out[c,b,g] = A[c,g,b] * final_scale (tiled transpose back)
// ---------------------------------------------------------------------------
__global__ __launch_bounds__(256) void k_out(const float* __restrict__ A,
                                             float* __restrict__ out,
                                             const uint32_t* __restrict__ slots,
                                             int mslot) {
  __shared__ float tile[32][33];
  const float sc = slot_scale(slots, mslot);
  const int g0 = blockIdx.x * 32, b0 = blockIdx.y * 32, c = blockIdx.z;
  const int tx = threadIdx.x;
  for (int j = threadIdx.y; j < 32; j += 8)
    tile[j][tx] = A[((size_t)c * G_ + g0 + j) * B_ + b0 + tx];  // tile[g][b]
  __syncthreads();
  for (int i = threadIdx.y; i < 32; i += 8)
    out[((size_t)c * B_ + b0 + i) * G_ + g0 + tx] = tile[tx][i] * sc;
}

extern "C" void kernel_launch(void* const* d_in, const int* in_sizes, int n_in,
                              void* d_out, int out_size, void* d_ws,
                              size_t ws_size, hipStream_t stream) {
  const float* x = (const float*)d_in[0];  // [B,G]
  const int* Idx = (const int*)d_in[1];    // [C,G,S,L]
  float* out = (float*)d_out;              // [C,B,G]

  char* ws = (char*)d_ws;
  uint32_t* slots = (uint32_t*)ws;                          // 7 max slots
  float* Xt = (float*)(ws + 256);                           // [G,B]   1 MB
  float* A = (float*)(ws + 256 + PERC_ * 4);                // [C,G,B] 4 MB
  float* Lb = (float*)(ws + 256 + PERC_ * 4 + NELEM_ * 4);  // [C,G,B] 4 MB

  hipMemsetAsync(slots, 0, 8 * sizeof(uint32_t), stream);

  dim3 tb(32, 8);
  k_init<<<dim3(G_ / 32, B_ / 32), tb, 0, stream>>>(x, Xt);

  for (int step = 0; step < NSTEP_; ++step) {
    const int prev = 2 * step;  // slot 0 == 0 -> scale 1 for step 0
    const int m1s = 2 * step + 1;
    const int m2s = 2 * step + 2;
    const float* src = (step == 0) ? Xt : A;
    const size_t cstride = (step == 0) ? (size_t)0 : PERC_;
    k_gather<<<CG_, 128, 0, stream>>>(src, cstride, Idx, Lb, slots, prev,
                                      m1s);
    k_elem<<<1024, 256, 0, stream>>>(A, Xt, Lb, slots, step, prev, m1s, m2s);
  }

  k_out<<<dim3(G_ / 32, B_ / 32, C_), tb, 0, stream>>>(A, out, slots,
                                                       2 * NSTEP_);
}